// Round 14
// baseline (59.732 us; speedup 1.0000x reference)
//
#include <hip/hip_runtime.h>
#include <hip/hip_bf16.h>
#include <stdint.h>

#define N_CLOTH     16384
#define N_OBS_VERTS 8192
#define N_OBS_FACES 16384

#define CHUNK 128                        // faces per chunk
#define NC    (N_OBS_FACES / CHUNK)      // 128 chunks

typedef short bf16x8 __attribute__((ext_vector_type(8)));
typedef float f32x4  __attribute__((ext_vector_type(4)));

__device__ __forceinline__ unsigned enc_f32(float x) {
    unsigned u = __float_as_uint(x);
    return (u & 0x80000000u) ? ~u : (u | 0x80000000u);   // monotone map
}

// 3-term bf16 split by truncation: x = h0 + h1 + h2 + eps, |eps| <= 2^-21 |x|
__device__ __forceinline__ void split3(float x, unsigned short* h) {
    float f1 = __uint_as_float(__float_as_uint(x) & 0xFFFF0000u);
    float r1 = x - f1;                                    // exact
    float f2 = __uint_as_float(__float_as_uint(r1) & 0xFFFF0000u);
    float r2 = r1 - f2;                                   // exact
    h[0] = (unsigned short)(__float_as_uint(f1) >> 16);
    h[1] = (unsigned short)(__float_as_uint(f2) >> 16);
    h[2] = (unsigned short)(__float_as_uint(r2) >> 16);   // truncated bf16
}

// ---------------------------------------------------------------------------
// K0: per-face prev center + w = 0.5||c||^2 -> faceA (fp32, for the exact
// scalar rescan) + packed bf16 split operands for MFMA:
//  K slots (21 used of 32):
//   A: [a1 a1 a2 a2 a1 a3 | 1 1 1 | 0...]   (a = split of NEGATED vert coords)
//   B: [b1 b2 b1 b2 b3 b1 | w1 w2 w3 | 0...]
//  sum = w - (a1b1 + a1b2 + a2b1 + a2b2 + a1b3 + a3b1) ~ 0.5||b||^2 - a.b
// Also zeroes out[0].
// ---------------------------------------------------------------------------
__global__ __launch_bounds__(256) void k_prep(
    const float* __restrict__ obs_prev, const int* __restrict__ faces,
    const float* __restrict__ cloth_prev,
    float4* __restrict__ faceA,
    unsigned short* __restrict__ Apk, unsigned short* __restrict__ Bpk,
    float* __restrict__ out)
{
    int i = blockIdx.x * 256 + threadIdx.x;
    if (i == 0) out[0] = 0.0f;

    // ---- face side ----
    {
        int i0 = faces[3 * i + 0];
        int i1 = faces[3 * i + 1];
        int i2 = faces[3 * i + 2];
        float ax = obs_prev[3 * i0 + 0], ay = obs_prev[3 * i0 + 1], az = obs_prev[3 * i0 + 2];
        float bx = obs_prev[3 * i1 + 0], by = obs_prev[3 * i1 + 1], bz = obs_prev[3 * i1 + 2];
        float cx = obs_prev[3 * i2 + 0], cy = obs_prev[3 * i2 + 1], cz = obs_prev[3 * i2 + 2];
        float pcx = (ax + bx + cx) * (1.0f / 3.0f);
        float pcy = (ay + by + cy) * (1.0f / 3.0f);
        float pcz = (az + bz + cz) * (1.0f / 3.0f);
        float w = 0.5f * (pcx * pcx + pcy * pcy + pcz * pcz);
        faceA[i] = make_float4(pcx, pcy, pcz, w);

        unsigned short sx[3], sy[3], sz[3], sw[3];
        split3(pcx, sx); split3(pcy, sy); split3(pcz, sz); split3(w, sw);
        unsigned short B[32];
#pragma unroll
        for (int j = 0; j < 32; ++j) B[j] = 0;
        B[0] = sx[0];  B[1] = sy[0];  B[2] = sz[0];     // b1
        B[3] = sx[1];  B[4] = sy[1];  B[5] = sz[1];     // b2
        B[6] = sx[0];  B[7] = sy[0];  B[8] = sz[0];     // b1
        B[9] = sx[1];  B[10] = sy[1]; B[11] = sz[1];    // b2
        B[12] = sx[2]; B[13] = sy[2]; B[14] = sz[2];    // b3
        B[15] = sx[0]; B[16] = sy[0]; B[17] = sz[0];    // b1
        B[18] = sw[0]; B[19] = sw[1]; B[20] = sw[2];    // w1 w2 w3
        int4* dst = (int4*)(Bpk + (size_t)i * 32);
        int4* src = (int4*)B;
        dst[0] = src[0]; dst[1] = src[1]; dst[2] = src[2]; dst[3] = src[3];
    }

    // ---- vertex side (negated coords) ----
    {
        float nx = -cloth_prev[3 * i + 0];
        float ny = -cloth_prev[3 * i + 1];
        float nz = -cloth_prev[3 * i + 2];
        unsigned short sx[3], sy[3], sz[3];
        split3(nx, sx); split3(ny, sy); split3(nz, sz);
        unsigned short A[32];
#pragma unroll
        for (int j = 0; j < 32; ++j) A[j] = 0;
        A[0] = sx[0];  A[1] = sy[0];  A[2] = sz[0];     // a1
        A[3] = sx[0];  A[4] = sy[0];  A[5] = sz[0];     // a1
        A[6] = sx[1];  A[7] = sy[1];  A[8] = sz[1];     // a2
        A[9] = sx[1];  A[10] = sy[1]; A[11] = sz[1];    // a2
        A[12] = sx[0]; A[13] = sy[0]; A[14] = sz[0];    // a1
        A[15] = sx[2]; A[16] = sy[2]; A[17] = sz[2];    // a3
        A[18] = 0x3F80; A[19] = 0x3F80; A[20] = 0x3F80; // bf16(1.0)
        int4* dst = (int4*)(Apk + (size_t)i * 32);
        int4* src = (int4*)A;
        dst[0] = src[0]; dst[1] = src[1]; dst[2] = src[2]; dst[3] = src[3];
    }
}

__device__ __forceinline__ f32x4 min4(f32x4 a, f32x4 b) {
    f32x4 r;
    r.x = fminf(a.x, b.x); r.y = fminf(a.y, b.y);
    r.z = fminf(a.z, b.z); r.w = fminf(a.w, b.w);
    return r;
}

// ---------------------------------------------------------------------------
// K1: MFMA NN scan. Block = 4 independent waves. Wave owns 128 verts x one
// 128-face chunk: 8 B-frags in regs, sweep 8 vert-tiles -> 64 MFMAs.
// Fragment layout (mfma_f32_16x16x32_bf16): A lane l: row=l&15, k=(l>>4)*8+j;
// B lane l: col=l&15, k=(l>>4)*8+j; C/D: col=lane&15, row=(lane>>4)*4+reg.
// Per vert-tile: min-tree over 8 acc (7 min4), 4-round shfl-xor col-collapse,
// float4 store of per-chunk minima -> chunkMin[c][n].
// ---------------------------------------------------------------------------
__global__ __launch_bounds__(256) void k_nn_mfma(
    const unsigned short* __restrict__ Apk,
    const unsigned short* __restrict__ Bpk,
    float* __restrict__ chunkMin)
{
    const int t = threadIdx.x;
    const int l = t & 63;
    const int wv = t >> 6;
    const int cid = blockIdx.y;
    const int fb = cid * CHUNK;
    const int vbase = blockIdx.x * 512 + wv * 128;
    const int lrow = l & 15;
    const int lkg = l >> 4;

    bf16x8 bfr[8];
#pragma unroll
    for (int nt = 0; nt < 8; ++nt) {
        int face = fb + nt * 16 + lrow;
        bfr[nt] = *(const bf16x8*)(Bpk + (size_t)face * 32 + lkg * 8);
    }

    const f32x4 z = {0.0f, 0.0f, 0.0f, 0.0f};

#pragma unroll
    for (int mt = 0; mt < 8; ++mt) {
        int vert = vbase + mt * 16 + lrow;
        bf16x8 afr = *(const bf16x8*)(Apk + (size_t)vert * 32 + lkg * 8);

        f32x4 a0 = __builtin_amdgcn_mfma_f32_16x16x32_bf16(afr, bfr[0], z, 0, 0, 0);
        f32x4 a1 = __builtin_amdgcn_mfma_f32_16x16x32_bf16(afr, bfr[1], z, 0, 0, 0);
        f32x4 a2 = __builtin_amdgcn_mfma_f32_16x16x32_bf16(afr, bfr[2], z, 0, 0, 0);
        f32x4 a3 = __builtin_amdgcn_mfma_f32_16x16x32_bf16(afr, bfr[3], z, 0, 0, 0);
        f32x4 a4 = __builtin_amdgcn_mfma_f32_16x16x32_bf16(afr, bfr[4], z, 0, 0, 0);
        f32x4 a5 = __builtin_amdgcn_mfma_f32_16x16x32_bf16(afr, bfr[5], z, 0, 0, 0);
        f32x4 a6 = __builtin_amdgcn_mfma_f32_16x16x32_bf16(afr, bfr[6], z, 0, 0, 0);
        f32x4 a7 = __builtin_amdgcn_mfma_f32_16x16x32_bf16(afr, bfr[7], z, 0, 0, 0);

        f32x4 m = min4(min4(min4(a0, a1), min4(a2, a3)),
                       min4(min4(a4, a5), min4(a6, a7)));

        // collapse across the 16 col-lanes (bits 0..3 of lane id)
#pragma unroll
        for (int d = 1; d < 16; d <<= 1) {
            m.x = fminf(m.x, __shfl_xor(m.x, d));
            m.y = fminf(m.y, __shfl_xor(m.y, d));
            m.z = fminf(m.z, __shfl_xor(m.z, d));
            m.w = fminf(m.w, __shfl_xor(m.w, d));
        }
        if (lrow == 0) {
            int vo = vbase + mt * 16 + lkg * 4;   // 4 consecutive verts (reg 0..3)
            *(float4*)(chunkMin + (size_t)cid * N_CLOTH + vo) =
                make_float4(m.x, m.y, m.z, m.w);
        }
    }
}

// ---------------------------------------------------------------------------
// K2: 4 threads per vertex (256 blocks x 256 thr).
// phase 1: f32 min over role's 32 chunkMin values (regs), cross-role shfl;
//          earliest chunk by register equality-rescan (MFMA values are
//          internally consistent; near-tie chunk flips are within tolerance).
// phase 2: FRESH exact scalar argmin inside the winning chunk: u64 keys
//          (mono(s)<<32)|idx -> smallest s, lowest index on ties.
// leader does the loss math; block sum; weight; atomicAdd -> out.
// ---------------------------------------------------------------------------
__global__ __launch_bounds__(256) void k_reduce(
    const float* __restrict__ cloth_prev,
    const float* __restrict__ cloth_pred,
    const float4* __restrict__ faceA,
    const float* __restrict__ chunkMin,
    const float* __restrict__ obs_pos,
    const int* __restrict__ faces,
    const int* __restrict__ iteration,
    float* __restrict__ out)
{
    const int t = threadIdx.x;
    const int r = t & 3;
    const int n = blockIdx.x * 64 + (t >> 2);

    // ---- phase 1 ----
    float vals[NC / 4];
    float m = 3.4e38f;
#pragma unroll
    for (int i = 0; i < NC / 4; ++i) {
        vals[i] = chunkMin[(size_t)(r * (NC / 4) + i) * N_CLOTH + n];
        m = fminf(vals[i], m);
    }
    m = fminf(m, __shfl_xor(m, 1));
    m = fminf(m, __shfl_xor(m, 2));

    int cbr = 0x7FFFFFFF;
#pragma unroll
    for (int i = NC / 4 - 1; i >= 0; --i)
        cbr = (vals[i] == m) ? r * (NC / 4) + i : cbr;
    {
        int o = __shfl_xor(cbr, 1); cbr = min(cbr, o);
        o = __shfl_xor(cbr, 2); cbr = min(cbr, o);
    }
    const int cb = cbr;

    // ---- phase 2: exact scalar argmin within chunk cb ----
    const float vx = cloth_prev[3 * n + 0];
    const float vy = cloth_prev[3 * n + 1];
    const float vz = cloth_prev[3 * n + 2];
    const int fbase = cb * CHUNK;
    unsigned long long bkey = 0xFFFFFFFFFFFFFFFFull;
#pragma unroll 8
    for (int qq = 0; qq < CHUNK / 4; ++qq) {
        int q = r * (CHUNK / 4) + qq;
        float4 b = faceA[fbase + q];
        float s = fmaf(-vx, b.x, b.w);
        s = fmaf(-vy, b.y, s);
        s = fmaf(-vz, b.z, s);
        unsigned long long k =
            ((unsigned long long)enc_f32(s) << 32) | (unsigned)(fbase + q);
        bkey = (k < bkey) ? k : bkey;
    }
    {
        unsigned long long o = __shfl_xor(bkey, 1); bkey = (o < bkey) ? o : bkey;
        o = __shfl_xor(bkey, 2); bkey = (o < bkey) ? o : bkey;
    }
    const int idx = (int)(unsigned)(bkey & 0xFFFFFFFFull);

    // ---- leader computes the loss term ----
    float val = 0.0f;
    if (r == 0) {
        int i0 = faces[3 * idx + 0];
        int i1 = faces[3 * idx + 1];
        int i2 = faces[3 * idx + 2];
        float ux = obs_pos[3 * i0 + 0], uy = obs_pos[3 * i0 + 1], uz = obs_pos[3 * i0 + 2];
        float wx1 = obs_pos[3 * i1 + 0], wy1 = obs_pos[3 * i1 + 1], wz1 = obs_pos[3 * i1 + 2];
        float wx2 = obs_pos[3 * i2 + 0], wy2 = obs_pos[3 * i2 + 1], wz2 = obs_pos[3 * i2 + 2];

        float fpx = (ux + wx1 + wx2) * (1.0f / 3.0f);
        float fpy = (uy + wy1 + wy2) * (1.0f / 3.0f);
        float fpz = (uz + wz1 + wz2) * (1.0f / 3.0f);

        float e1x = wx1 - ux, e1y = wy1 - uy, e1z = wz1 - uz;
        float e2x = wx2 - ux, e2y = wy2 - uy, e2z = wz2 - uz;
        float nx = e1y * e2z - e1z * e2y;
        float ny = e1z * e2x - e1x * e2z;
        float nz = e1x * e2y - e1y * e2x;
        float nrm = sqrtf(nx * nx + ny * ny + nz * nz);
        float inv = 1.0f / fmaxf(nrm, 1e-12f);

        float px = cloth_pred[3 * n + 0];
        float py = cloth_pred[3 * n + 1];
        float pz = cloth_pred[3 * n + 2];
        float d = (px - fpx) * nx * inv + (py - fpy) * ny * inv + (pz - fpz) * nz * inv;
        float tt = fmaxf(1e-3f - d, 0.0f);
        val = tt * tt * tt;
    }

    __shared__ float red[256];
    red[t] = val;
    __syncthreads();
    for (int s = 128; s > 0; s >>= 1) {
        if (t < s) red[t] += red[t + s];
        __syncthreads();
    }
    if (t == 0) {
        int it = iteration[0];
        float itf = fmaxf((float)(it - 50000), 0.0f);
        float prog = fminf(itf * (1.0f / 100000.0f), 1.0f);
        float w = 1.0f + (5000.0f - 1.0f) * prog;
        atomicAdd(out, red[0] * w);
    }
}

extern "C" void kernel_launch(void* const* d_in, const int* in_sizes, int n_in,
                              void* d_out, int out_size, void* d_ws, size_t ws_size,
                              hipStream_t stream) {
    const float* obs_pos    = (const float*)d_in[0];
    const float* obs_prev   = (const float*)d_in[1];
    const int*   faces      = (const int*)d_in[2];
    const float* cloth_prev = (const float*)d_in[3];
    const float* cloth_pred = (const float*)d_in[4];
    const int*   iteration  = (const int*)d_in[5];
    float* out = (float*)d_out;

    char* ws = (char*)d_ws;
    float4*         faceA    = (float4*)(ws);                    // 256 KB
    unsigned short* Apk      = (unsigned short*)(ws + 262144);   // 1 MB
    unsigned short* Bpk      = (unsigned short*)(ws + 1310720);  // 1 MB
    float*          chunkMin = (float*)(ws + 2359296);           // 8.4 MB [NC][N]

    k_prep<<<N_OBS_FACES / 256, 256, 0, stream>>>(
        obs_prev, faces, cloth_prev, faceA, Apk, Bpk, out);
    k_nn_mfma<<<dim3(N_CLOTH / 512, NC), 256, 0, stream>>>(Apk, Bpk, chunkMin);
    k_reduce<<<N_CLOTH * 4 / 256, 256, 0, stream>>>(
        cloth_prev, cloth_pred, faceA, chunkMin, obs_pos, faces, iteration, out);
}

// Round 15
// 48.237 us; speedup vs baseline: 1.2383x; 1.2383x over previous
//
#include <hip/hip_runtime.h>
#include <hip/hip_bf16.h>
#include <stdint.h>

#define N_CLOTH     16384
#define N_OBS_VERTS 8192
#define N_OBS_FACES 16384

#define CHUNK 128                        // faces per chunk
#define NC    (N_OBS_FACES / CHUNK)      // 128 chunks

typedef short bf16x8 __attribute__((ext_vector_type(8)));
typedef float f32x4  __attribute__((ext_vector_type(4)));

__device__ __forceinline__ unsigned enc_f32(float x) {
    unsigned u = __float_as_uint(x);
    return (u & 0x80000000u) ? ~u : (u | 0x80000000u);   // monotone map
}

// 3-term bf16 split by truncation: x = h0 + h1 + h2 + eps, |eps| <= 2^-21 |x|
__device__ __forceinline__ void split3(float x, unsigned short* h) {
    float f1 = __uint_as_float(__float_as_uint(x) & 0xFFFF0000u);
    float r1 = x - f1;                                    // exact
    float f2 = __uint_as_float(__float_as_uint(r1) & 0xFFFF0000u);
    float r2 = r1 - f2;                                   // exact
    h[0] = (unsigned short)(__float_as_uint(f1) >> 16);
    h[1] = (unsigned short)(__float_as_uint(f2) >> 16);
    h[2] = (unsigned short)(__float_as_uint(r2) >> 16);   // truncated bf16
}

// ---------------------------------------------------------------------------
// K0: per-face prev center + w = 0.5||c||^2 -> faceA (fp32, exact rescan) +
// packed bf16 split operands (21 of 32 K slots):
//   vert V: [a1 a1 a2 a2 a1 a3 | 1 1 1 | 0...]   (a = NEGATED vert coords)
//   face F: [b1 b2 b1 b2 b3 b1 | w1 w2 w3 | 0...]
//   sum_k F[k]V[k] = w - (a1b1 + a1b2 + a2b1 + a2b2 + a1b3 + a3b1)
// Also zeroes out[0]. (Identical to R14 -- verified absmax 0.0.)
// ---------------------------------------------------------------------------
__global__ __launch_bounds__(256) void k_prep(
    const float* __restrict__ obs_prev, const int* __restrict__ faces,
    const float* __restrict__ cloth_prev,
    float4* __restrict__ faceA,
    unsigned short* __restrict__ Apk, unsigned short* __restrict__ Bpk,
    float* __restrict__ out)
{
    int i = blockIdx.x * 256 + threadIdx.x;
    if (i == 0) out[0] = 0.0f;

    // ---- face side ----
    {
        int i0 = faces[3 * i + 0];
        int i1 = faces[3 * i + 1];
        int i2 = faces[3 * i + 2];
        float ax = obs_prev[3 * i0 + 0], ay = obs_prev[3 * i0 + 1], az = obs_prev[3 * i0 + 2];
        float bx = obs_prev[3 * i1 + 0], by = obs_prev[3 * i1 + 1], bz = obs_prev[3 * i1 + 2];
        float cx = obs_prev[3 * i2 + 0], cy = obs_prev[3 * i2 + 1], cz = obs_prev[3 * i2 + 2];
        float pcx = (ax + bx + cx) * (1.0f / 3.0f);
        float pcy = (ay + by + cy) * (1.0f / 3.0f);
        float pcz = (az + bz + cz) * (1.0f / 3.0f);
        float w = 0.5f * (pcx * pcx + pcy * pcy + pcz * pcz);
        faceA[i] = make_float4(pcx, pcy, pcz, w);

        unsigned short sx[3], sy[3], sz[3], sw[3];
        split3(pcx, sx); split3(pcy, sy); split3(pcz, sz); split3(w, sw);
        unsigned short B[32];
#pragma unroll
        for (int j = 0; j < 32; ++j) B[j] = 0;
        B[0] = sx[0];  B[1] = sy[0];  B[2] = sz[0];     // b1
        B[3] = sx[1];  B[4] = sy[1];  B[5] = sz[1];     // b2
        B[6] = sx[0];  B[7] = sy[0];  B[8] = sz[0];     // b1
        B[9] = sx[1];  B[10] = sy[1]; B[11] = sz[1];    // b2
        B[12] = sx[2]; B[13] = sy[2]; B[14] = sz[2];    // b3
        B[15] = sx[0]; B[16] = sy[0]; B[17] = sz[0];    // b1
        B[18] = sw[0]; B[19] = sw[1]; B[20] = sw[2];    // w1 w2 w3
        int4* dst = (int4*)(Bpk + (size_t)i * 32);
        int4* src = (int4*)B;
        dst[0] = src[0]; dst[1] = src[1]; dst[2] = src[2]; dst[3] = src[3];
    }

    // ---- vertex side (negated coords) ----
    {
        float nx = -cloth_prev[3 * i + 0];
        float ny = -cloth_prev[3 * i + 1];
        float nz = -cloth_prev[3 * i + 2];
        unsigned short sx[3], sy[3], sz[3];
        split3(nx, sx); split3(ny, sy); split3(nz, sz);
        unsigned short A[32];
#pragma unroll
        for (int j = 0; j < 32; ++j) A[j] = 0;
        A[0] = sx[0];  A[1] = sy[0];  A[2] = sz[0];     // a1
        A[3] = sx[0];  A[4] = sy[0];  A[5] = sz[0];     // a1
        A[6] = sx[1];  A[7] = sy[1];  A[8] = sz[1];     // a2
        A[9] = sx[1];  A[10] = sy[1]; A[11] = sz[1];    // a2
        A[12] = sx[0]; A[13] = sy[0]; A[14] = sz[0];    // a1
        A[15] = sx[2]; A[16] = sy[2]; A[17] = sz[2];    // a3
        A[18] = 0x3F80; A[19] = 0x3F80; A[20] = 0x3F80; // bf16(1.0)
        int4* dst = (int4*)(Apk + (size_t)i * 32);
        int4* src = (int4*)A;
        dst[0] = src[0]; dst[1] = src[1]; dst[2] = src[2]; dst[3] = src[3];
    }
}

__device__ __forceinline__ f32x4 min4(f32x4 a, f32x4 b) {
    f32x4 r;
    r.x = fminf(a.x, b.x); r.y = fminf(a.y, b.y);
    r.z = fminf(a.z, b.z); r.w = fminf(a.w, b.w);
    return r;
}

// ---------------------------------------------------------------------------
// K1: MFMA NN scan, SWAPPED orientation: A = faces (rows), B = verts (cols).
// D[m][n] = sum_k F_face(m)[k] * V_vert(n)[k] = s(vert n, face m).
// Wave owns one chunk's 8 A-frags in regs; sweeps 8 vert-tiles with a 1-deep
// prefetch pipeline. Per tile: 8 MFMAs -> 7xmin4 (28 v_min) -> 3 in-lane min
// -> 2 shfl_xor(16/32) rounds -> coalesced 16-lane store. Min over the
// chunk's 128 faces is reg-local (rows live in regs), not a column collapse.
// Fragment layout (verified by R14 absmax 0.0): A lane l: row=l&15,
// k=(l>>4)*8+j; B lane l: col=l&15, k=(l>>4)*8+j; C/D: col=lane&15,
// row=(lane>>4)*4+reg.
// ---------------------------------------------------------------------------
__global__ __launch_bounds__(256) void k_nn_mfma(
    const unsigned short* __restrict__ Apk,   // vert packing (B operand now)
    const unsigned short* __restrict__ Bpk,   // face packing (A operand now)
    float* __restrict__ chunkMin)
{
    const int t = threadIdx.x;
    const int l = t & 63;
    const int wv = t >> 6;
    const int cid = blockIdx.y;
    const int fb = cid * CHUNK;
    const int vbase = blockIdx.x * 512 + wv * 128;
    const int lrow = l & 15;
    const int lkg = l >> 4;

    // resident A-frags: the chunk's 128 faces (8 row-tiles of 16)
    bf16x8 afr[8];
#pragma unroll
    for (int nt = 0; nt < 8; ++nt)
        afr[nt] = *(const bf16x8*)(Bpk + (size_t)(fb + nt * 16 + lrow) * 32 + lkg * 8);

    const f32x4 z = {0.0f, 0.0f, 0.0f, 0.0f};

    // 1-deep pipeline over 8 vert-tiles
    bf16x8 bcur = *(const bf16x8*)(Apk + (size_t)(vbase + lrow) * 32 + lkg * 8);
#pragma unroll
    for (int mt = 0; mt < 8; ++mt) {
        bf16x8 bnext = bcur;
        if (mt < 7)
            bnext = *(const bf16x8*)(Apk +
                     (size_t)(vbase + (mt + 1) * 16 + lrow) * 32 + lkg * 8);

        f32x4 a0 = __builtin_amdgcn_mfma_f32_16x16x32_bf16(afr[0], bcur, z, 0, 0, 0);
        f32x4 a1 = __builtin_amdgcn_mfma_f32_16x16x32_bf16(afr[1], bcur, z, 0, 0, 0);
        f32x4 a2 = __builtin_amdgcn_mfma_f32_16x16x32_bf16(afr[2], bcur, z, 0, 0, 0);
        f32x4 a3 = __builtin_amdgcn_mfma_f32_16x16x32_bf16(afr[3], bcur, z, 0, 0, 0);
        f32x4 a4 = __builtin_amdgcn_mfma_f32_16x16x32_bf16(afr[4], bcur, z, 0, 0, 0);
        f32x4 a5 = __builtin_amdgcn_mfma_f32_16x16x32_bf16(afr[5], bcur, z, 0, 0, 0);
        f32x4 a6 = __builtin_amdgcn_mfma_f32_16x16x32_bf16(afr[6], bcur, z, 0, 0, 0);
        f32x4 a7 = __builtin_amdgcn_mfma_f32_16x16x32_bf16(afr[7], bcur, z, 0, 0, 0);

        f32x4 m = min4(min4(min4(a0, a1), min4(a2, a3)),
                       min4(min4(a4, a5), min4(a6, a7)));
        // in-lane: min over this lane's 4 face-rows
        float mm = fminf(fminf(m.x, m.y), fminf(m.z, m.w));
        // cross row-group (lane bits 4,5): full 128-face min for vert col l&15
        mm = fminf(mm, __shfl_xor(mm, 16));
        mm = fminf(mm, __shfl_xor(mm, 32));

        if (l < 16)
            chunkMin[(size_t)cid * N_CLOTH + (vbase + mt * 16 + l)] = mm;

        bcur = bnext;
    }
}

// ---------------------------------------------------------------------------
// K2: 4 threads per vertex (256 blocks x 256 thr).
// phase 1: f32 min over role's 32 chunkMin values (regs), cross-role shfl;
//          earliest chunk by register equality-rescan.
// phase 2: FRESH exact scalar argmin inside the winning chunk: u64 keys
//          (mono(s)<<32)|idx -> smallest s, lowest index on ties.
// leader does the loss math; block sum; weight; atomicAdd -> out.
// ---------------------------------------------------------------------------
__global__ __launch_bounds__(256) void k_reduce(
    const float* __restrict__ cloth_prev,
    const float* __restrict__ cloth_pred,
    const float4* __restrict__ faceA,
    const float* __restrict__ chunkMin,
    const float* __restrict__ obs_pos,
    const int* __restrict__ faces,
    const int* __restrict__ iteration,
    float* __restrict__ out)
{
    const int t = threadIdx.x;
    const int r = t & 3;
    const int n = blockIdx.x * 64 + (t >> 2);

    // ---- phase 1 ----
    float vals[NC / 4];
    float m = 3.4e38f;
#pragma unroll
    for (int i = 0; i < NC / 4; ++i) {
        vals[i] = chunkMin[(size_t)(r * (NC / 4) + i) * N_CLOTH + n];
        m = fminf(vals[i], m);
    }
    m = fminf(m, __shfl_xor(m, 1));
    m = fminf(m, __shfl_xor(m, 2));

    int cbr = 0x7FFFFFFF;
#pragma unroll
    for (int i = NC / 4 - 1; i >= 0; --i)
        cbr = (vals[i] == m) ? r * (NC / 4) + i : cbr;
    {
        int o = __shfl_xor(cbr, 1); cbr = min(cbr, o);
        o = __shfl_xor(cbr, 2); cbr = min(cbr, o);
    }
    const int cb = cbr;

    // ---- phase 2: exact scalar argmin within chunk cb ----
    const float vx = cloth_prev[3 * n + 0];
    const float vy = cloth_prev[3 * n + 1];
    const float vz = cloth_prev[3 * n + 2];
    const int fbase = cb * CHUNK;
    unsigned long long bkey = 0xFFFFFFFFFFFFFFFFull;
#pragma unroll 8
    for (int qq = 0; qq < CHUNK / 4; ++qq) {
        int q = r * (CHUNK / 4) + qq;
        float4 b = faceA[fbase + q];
        float s = fmaf(-vx, b.x, b.w);
        s = fmaf(-vy, b.y, s);
        s = fmaf(-vz, b.z, s);
        unsigned long long k =
            ((unsigned long long)enc_f32(s) << 32) | (unsigned)(fbase + q);
        bkey = (k < bkey) ? k : bkey;
    }
    {
        unsigned long long o = __shfl_xor(bkey, 1); bkey = (o < bkey) ? o : bkey;
        o = __shfl_xor(bkey, 2); bkey = (o < bkey) ? o : bkey;
    }
    const int idx = (int)(unsigned)(bkey & 0xFFFFFFFFull);

    // ---- leader computes the loss term ----
    float val = 0.0f;
    if (r == 0) {
        int i0 = faces[3 * idx + 0];
        int i1 = faces[3 * idx + 1];
        int i2 = faces[3 * idx + 2];
        float ux = obs_pos[3 * i0 + 0], uy = obs_pos[3 * i0 + 1], uz = obs_pos[3 * i0 + 2];
        float wx1 = obs_pos[3 * i1 + 0], wy1 = obs_pos[3 * i1 + 1], wz1 = obs_pos[3 * i1 + 2];
        float wx2 = obs_pos[3 * i2 + 0], wy2 = obs_pos[3 * i2 + 1], wz2 = obs_pos[3 * i2 + 2];

        float fpx = (ux + wx1 + wx2) * (1.0f / 3.0f);
        float fpy = (uy + wy1 + wy2) * (1.0f / 3.0f);
        float fpz = (uz + wz1 + wz2) * (1.0f / 3.0f);

        float e1x = wx1 - ux, e1y = wy1 - uy, e1z = wz1 - uz;
        float e2x = wx2 - ux, e2y = wy2 - uy, e2z = wz2 - uz;
        float nx = e1y * e2z - e1z * e2y;
        float ny = e1z * e2x - e1x * e2z;
        float nz = e1x * e2y - e1y * e2x;
        float nrm = sqrtf(nx * nx + ny * ny + nz * nz);
        float inv = 1.0f / fmaxf(nrm, 1e-12f);

        float px = cloth_pred[3 * n + 0];
        float py = cloth_pred[3 * n + 1];
        float pz = cloth_pred[3 * n + 2];
        float d = (px - fpx) * nx * inv + (py - fpy) * ny * inv + (pz - fpz) * nz * inv;
        float tt = fmaxf(1e-3f - d, 0.0f);
        val = tt * tt * tt;
    }

    __shared__ float red[256];
    red[t] = val;
    __syncthreads();
    for (int s = 128; s > 0; s >>= 1) {
        if (t < s) red[t] += red[t + s];
        __syncthreads();
    }
    if (t == 0) {
        int it = iteration[0];
        float itf = fmaxf((float)(it - 50000), 0.0f);
        float prog = fminf(itf * (1.0f / 100000.0f), 1.0f);
        float w = 1.0f + (5000.0f - 1.0f) * prog;
        atomicAdd(out, red[0] * w);
    }
}

extern "C" void kernel_launch(void* const* d_in, const int* in_sizes, int n_in,
                              void* d_out, int out_size, void* d_ws, size_t ws_size,
                              hipStream_t stream) {
    const float* obs_pos    = (const float*)d_in[0];
    const float* obs_prev   = (const float*)d_in[1];
    const int*   faces      = (const int*)d_in[2];
    const float* cloth_prev = (const float*)d_in[3];
    const float* cloth_pred = (const float*)d_in[4];
    const int*   iteration  = (const int*)d_in[5];
    float* out = (float*)d_out;

    char* ws = (char*)d_ws;
    float4*         faceA    = (float4*)(ws);                    // 256 KB
    unsigned short* Apk      = (unsigned short*)(ws + 262144);   // 1 MB
    unsigned short* Bpk      = (unsigned short*)(ws + 1310720);  // 1 MB
    float*          chunkMin = (float*)(ws + 2359296);           // 8.4 MB [NC][N]

    k_prep<<<N_OBS_FACES / 256, 256, 0, stream>>>(
        obs_prev, faces, cloth_prev, faceA, Apk, Bpk, out);
    k_nn_mfma<<<dim3(N_CLOTH / 512, NC), 256, 0, stream>>>(Apk, Bpk, chunkMin);
    k_reduce<<<N_CLOTH * 4 / 256, 256, 0, stream>>>(
        cloth_prev, cloth_pred, faceA, chunkMin, obs_pos, faces, iteration, out);
}

// Round 16
// 40.750 us; speedup vs baseline: 1.4658x; 1.1837x over previous
//
#include <hip/hip_runtime.h>
#include <hip/hip_bf16.h>
#include <stdint.h>

#define N_CLOTH     16384
#define N_OBS_VERTS 8192
#define N_OBS_FACES 16384

#define CHUNK 128                        // faces per chunk (LDS tile = 2KB)
#define NC    (N_OBS_FACES / CHUNK)      // 128 chunks
#define VPT   8                          // vertices per thread
#define TB    256                        // threads per block
#define VBLK  (N_CLOTH / (TB * VPT))     // 8 vertex-blocks -> grid 8x128 = 1024 blocks

// ---------------------------------------------------------------------------
// K1 (fused faces + NN): each block builds its chunk's 128 prev-face centers
// in LDS from L2-resident gathers (threads 0..127); blocks with bv==0 also
// persist the tile to faceA (single, bit-identical source for k_reduce) and
// zero the output accumulator. Main loop: value-only scan, 14 VALU / 4 pairs:
//   12 fma + v_min3(s0,s1,s2) + v_min3(m,s3,best)
// chunkMin[c][n] = min_{f in chunk c} s(n,f),  s = 0.5||b||^2 - a.b
// (monotone in d2 per vertex; min3/fminf return one of their inputs, so the
//  min is bit-equal to some s -- k_reduce relies on that for index recovery)
// ---------------------------------------------------------------------------
__global__ __launch_bounds__(TB) void k_nn(
    const float* __restrict__ cloth_prev,
    const float* __restrict__ obs_prev,
    const int* __restrict__ faces,
    float4* __restrict__ faceA,
    float* __restrict__ chunkMin,          // [NC][N_CLOTH]
    float* __restrict__ out)
{
    __shared__ float4 tile[CHUNK];
    const int t = threadIdx.x;
    const int bv = blockIdx.x;      // vertex block 0..VBLK-1
    const int c  = blockIdx.y;      // face chunk   0..NC-1
    const int fbase = c * CHUNK;

    // build this chunk's prev-center tile (threads 0..CHUNK-1, one face each)
    if (t < CHUNK) {
        int f = fbase + t;
        int i0 = faces[3 * f + 0];
        int i1 = faces[3 * f + 1];
        int i2 = faces[3 * f + 2];
        float ax = obs_prev[3 * i0 + 0], ay = obs_prev[3 * i0 + 1], az = obs_prev[3 * i0 + 2];
        float bx = obs_prev[3 * i1 + 0], by = obs_prev[3 * i1 + 1], bz = obs_prev[3 * i1 + 2];
        float cx = obs_prev[3 * i2 + 0], cy = obs_prev[3 * i2 + 1], cz = obs_prev[3 * i2 + 2];
        float pcx = (ax + bx + cx) * (1.0f / 3.0f);
        float pcy = (ay + by + cy) * (1.0f / 3.0f);
        float pcz = (az + bz + cz) * (1.0f / 3.0f);
        float b2h = 0.5f * (pcx * pcx + pcy * pcy + pcz * pcz);
        float4 v = make_float4(pcx, pcy, pcz, b2h);
        tile[t] = v;
        if (bv == 0) {
            faceA[f] = v;                       // persist for k_reduce (bit-identical)
            if (f == 0) out[0] = 0.0f;          // zero accumulator (pre-k_reduce)
        }
    }

    float vx[VPT], vy[VPT], vz[VPT], best[VPT];
#pragma unroll
    for (int j = 0; j < VPT; ++j) {
        int n = bv * (TB * VPT) + j * TB + t;
        vx[j] = cloth_prev[3 * n + 0];
        vy[j] = cloth_prev[3 * n + 1];
        vz[j] = cloth_prev[3 * n + 2];
        best[j] = 3.4e38f;
    }
    __syncthreads();

#pragma unroll 2
    for (int gi = 0; gi < CHUNK / 4; ++gi) {
        float4 b0 = tile[4 * gi + 0];
        float4 b1 = tile[4 * gi + 1];
        float4 b2 = tile[4 * gi + 2];
        float4 b3 = tile[4 * gi + 3];
#pragma unroll
        for (int j = 0; j < VPT; ++j) {
            float s0 = fmaf(-vx[j], b0.x, b0.w);
            s0 = fmaf(-vy[j], b0.y, s0);
            s0 = fmaf(-vz[j], b0.z, s0);
            float s1 = fmaf(-vx[j], b1.x, b1.w);
            s1 = fmaf(-vy[j], b1.y, s1);
            s1 = fmaf(-vz[j], b1.z, s1);
            float s2 = fmaf(-vx[j], b2.x, b2.w);
            s2 = fmaf(-vy[j], b2.y, s2);
            s2 = fmaf(-vz[j], b2.z, s2);
            float s3 = fmaf(-vx[j], b3.x, b3.w);
            s3 = fmaf(-vy[j], b3.y, s3);
            s3 = fmaf(-vz[j], b3.z, s3);
            float m = fminf(fminf(s0, s1), s2);       // v_min3_f32
            best[j] = fminf(fminf(m, s3), best[j]);   // v_min3_f32
        }
    }

#pragma unroll
    for (int j = 0; j < VPT; ++j) {
        int n = bv * (TB * VPT) + j * TB + t;
        chunkMin[(size_t)c * N_CLOTH + n] = best[j];
    }
}

// ---------------------------------------------------------------------------
// K2: 4 threads per vertex (grid 256 blocks x 256 thr).
// phase 1: f32 min over this role's 32 chunks (registers, full unroll),
//          cross-role min via shfl; earliest chunk by register equality-rescan
//          (roles own contiguous chunk ranges -> cross-role min-index is the
//          global earliest chunk == jnp.argmin tie-break order).
// phase 2: rescan the 128 faces of the winning chunk (32/role) with the
//          bit-identical scalar fmaf chain; descending select -> lowest q.
// leader does the loss math; block sum; weight; atomicAdd -> out.
// ---------------------------------------------------------------------------
__global__ __launch_bounds__(256) void k_reduce(
    const float* __restrict__ cloth_prev,
    const float* __restrict__ cloth_pred,
    const float4* __restrict__ faceA,
    const float* __restrict__ chunkMin,
    const float* __restrict__ obs_pos,
    const int* __restrict__ faces,
    const int* __restrict__ iteration,
    float* __restrict__ out)
{
    const int t = threadIdx.x;
    const int r = t & 3;                       // role within vertex
    const int n = blockIdx.x * 64 + (t >> 2);  // vertex id

    // ---- phase 1: f32 min over this role's 32 chunks (registers) ----
    float vals[NC / 4];
    float m = 3.4e38f;
#pragma unroll
    for (int i = 0; i < NC / 4; ++i) {
        vals[i] = chunkMin[(size_t)(r * (NC / 4) + i) * N_CLOTH + n];
        m = fminf(vals[i], m);
    }
    m = fminf(m, __shfl_xor(m, 1));
    m = fminf(m, __shfl_xor(m, 2));          // global min value (bit-exact)

    int cbr = 0x7FFFFFFF;
#pragma unroll
    for (int i = NC / 4 - 1; i >= 0; --i)
        cbr = (vals[i] == m) ? r * (NC / 4) + i : cbr;   // lowest i in role
    {
        int o = __shfl_xor(cbr, 1); cbr = min(cbr, o);
        o = __shfl_xor(cbr, 2); cbr = min(cbr, o);       // earliest chunk
    }
    const int cb = cbr;

    // ---- phase 2: lowest face in chunk cb with s == m (bit-exact) ----
    const float vx = cloth_prev[3 * n + 0];
    const float vy = cloth_prev[3 * n + 1];
    const float vz = cloth_prev[3 * n + 2];
    const int fbase = cb * CHUNK;
    int match = 0x7FFFFFFF;
#pragma unroll 8
    for (int qq = CHUNK / 4 - 1; qq >= 0; --qq) {
        int q = r * (CHUNK / 4) + qq;
        float4 b = faceA[fbase + q];
        float s = fmaf(-vx, b.x, b.w);
        s = fmaf(-vy, b.y, s);
        s = fmaf(-vz, b.z, s);
        match = (s == m) ? q : match;          // descending -> lowest q wins
    }
    {
        int o = __shfl_xor(match, 1); match = min(match, o);
        o = __shfl_xor(match, 2); match = min(match, o);
    }
    const int idx = fbase + match;

    // ---- leader computes the loss term ----
    float val = 0.0f;
    if (r == 0) {
        int i0 = faces[3 * idx + 0];
        int i1 = faces[3 * idx + 1];
        int i2 = faces[3 * idx + 2];
        float ux = obs_pos[3 * i0 + 0], uy = obs_pos[3 * i0 + 1], uz = obs_pos[3 * i0 + 2];
        float wx1 = obs_pos[3 * i1 + 0], wy1 = obs_pos[3 * i1 + 1], wz1 = obs_pos[3 * i1 + 2];
        float wx2 = obs_pos[3 * i2 + 0], wy2 = obs_pos[3 * i2 + 1], wz2 = obs_pos[3 * i2 + 2];

        float fpx = (ux + wx1 + wx2) * (1.0f / 3.0f);
        float fpy = (uy + wy1 + wy2) * (1.0f / 3.0f);
        float fpz = (uz + wz1 + wz2) * (1.0f / 3.0f);

        float e1x = wx1 - ux, e1y = wy1 - uy, e1z = wz1 - uz;
        float e2x = wx2 - ux, e2y = wy2 - uy, e2z = wz2 - uz;
        float nx = e1y * e2z - e1z * e2y;
        float ny = e1z * e2x - e1x * e2z;
        float nz = e1x * e2y - e1y * e2x;
        float nrm = sqrtf(nx * nx + ny * ny + nz * nz);
        float inv = 1.0f / fmaxf(nrm, 1e-12f);

        float px = cloth_pred[3 * n + 0];
        float py = cloth_pred[3 * n + 1];
        float pz = cloth_pred[3 * n + 2];
        float d = (px - fpx) * nx * inv + (py - fpy) * ny * inv + (pz - fpz) * nz * inv;
        float tt = fmaxf(1e-3f - d, 0.0f);
        val = tt * tt * tt;
    }

    __shared__ float red[256];
    red[t] = val;
    __syncthreads();
    for (int s = 128; s > 0; s >>= 1) {
        if (t < s) red[t] += red[t + s];
        __syncthreads();
    }
    if (t == 0) {
        int it = iteration[0];
        float itf = fmaxf((float)(it - 50000), 0.0f);
        float prog = fminf(itf * (1.0f / 100000.0f), 1.0f);
        float w = 1.0f + (5000.0f - 1.0f) * prog;
        atomicAdd(out, red[0] * w);
    }
}

extern "C" void kernel_launch(void* const* d_in, const int* in_sizes, int n_in,
                              void* d_out, int out_size, void* d_ws, size_t ws_size,
                              hipStream_t stream) {
    const float* obs_pos    = (const float*)d_in[0];
    const float* obs_prev   = (const float*)d_in[1];
    const int*   faces      = (const int*)d_in[2];
    const float* cloth_prev = (const float*)d_in[3];
    const float* cloth_pred = (const float*)d_in[4];
    const int*   iteration  = (const int*)d_in[5];
    float* out = (float*)d_out;

    char* ws = (char*)d_ws;
    float4* faceA    = (float4*)(ws);                 // 256 KB
    float*  chunkMin = (float*)(ws + 262144);         // 8.4 MB [NC][N]

    k_nn<<<dim3(VBLK, NC), TB, 0, stream>>>(
        cloth_prev, obs_prev, faces, faceA, chunkMin, out);
    k_reduce<<<N_CLOTH * 4 / 256, 256, 0, stream>>>(
        cloth_prev, cloth_pred, faceA, chunkMin, obs_pos, faces, iteration, out);
}